// Round 20
// baseline (55.323 us; speedup 1.0000x reference)
//
#include <hip/hip_runtime.h>

// SimpleHybridModel via MFMA, all-transposed chaining:
//  conv1d(k=3,SAME,relu) -> SimpleRNN(16,tanh) -> dense(8,relu) -> dense(1)
//
// R20 = R18 (39.7us best) with ONLY the staging access pattern changed:
//  - R18 staged via 35 float2/lane at 280B lane stride: each wave VMEM instr
//    touches ~64 distinct 64B lines -> ~2240 L1 transactions/wave -> ~31k cy
//    per CU generation. That matches the observed 41k-cy wave lifetime (8x
//    the issue work) -> staging L1-transaction wall is the limiter.
//  - R20: tid-linear float4 loads (1120 groups, 18 rounds; each 64B line
//    touched EXACTLY once -> ~280 transactions/wave) + scatter-convert via
//    4x ds_write_b16 per group (lane stride 8B -> <=4-way banks, mild).
//  - R19's reg-held pipeline failed (compiler sank loads, VGPR=64): no
//    pipelining here, pure access-pattern fix. Clean A/B vs R18.
// Retained from R18: single-wave blocks (BLK=64, 32 elems, 2 chains/lane,
// 14 blocks/CU = 448 resident elems), no __syncthreads (lgkmcnt fence +
// sched_barrier, rule #18), 21-slot f16 element layout (slot0 pad
// (0..0,1.0h); slot l+g read as one aligned ds_read_b128; elem e row-20
// read = elem e+1's pad; dummy 1.0 at half 7 feeds the k=31 conv-bias tap;
// 2 guard slots), conv bias rides MFMA, 2*log2e folded into A2/AU/rnn_b,
// rcp+exp2 tanh, packed cvts in compute, head via MFMA.

#define BLK 64
#define LSEQ 20
#define EPW 84              // dwords per element: 21 slots * 4 (336 B)
#define LOG2E2 2.8853900817779268f

typedef _Float16 f16;
typedef __fp16   fp16x2 __attribute__((ext_vector_type(2)));
typedef _Float16 f16x4 __attribute__((ext_vector_type(4)));
typedef _Float16 f16x8 __attribute__((ext_vector_type(8)));
typedef float    f32x4 __attribute__((ext_vector_type(4)));

union UB128 { uint4 q; f16x8 v; };
union UB64  { f16x4 v; fp16x2 p[2]; };

__global__ __launch_bounds__(BLK, 4) void hybrid_fwd(
    const float* __restrict__ x,
    const float* __restrict__ conv_w, const float* __restrict__ conv_b,
    const float* __restrict__ rnn_w,  const float* __restrict__ rnn_u,
    const float* __restrict__ rnn_b,
    const float* __restrict__ d1_w,   const float* __restrict__ d1_b,
    const float* __restrict__ out_w,  const float* __restrict__ out_b,
    float* __restrict__ out)
{
    __shared__ __align__(16) uint xs[32 * EPW + 8];   // 10784 B

    const int lane = threadIdx.x;                 // single wave
    const int b16  = lane & 15, g = lane >> 4;
    const long BE  = (long)blockIdx.x * 32;       // block's first elem

    // ---- weight fragments FIRST (VMEM latency overlaps staging below) ----
    f16x8 A1;
    #pragma unroll
    for (int t = 0; t < 8; ++t) {
        float wv = conv_w[min(g * 7 + t, 20) * 16 + b16];
        float sel = (g < 3 && t < 7) ? wv
                  : ((g == 3 && t == 7) ? conv_b[b16] : 0.f);
        A1[t] = (f16)sel;
    }
    f16x4 A2, AU;
    f32x4 rbp;
    #pragma unroll
    for (int t = 0; t < 4; ++t) {
        A2[t]  = (f16)(LOG2E2 * rnn_w[(4 * g + t) * 16 + b16]);
        AU[t]  = (f16)(LOG2E2 * rnn_u[(4 * g + t) * 16 + b16]);
        rbp[t] = LOG2E2 * rnn_b[4 * g + t];
    }
    f16x4 A3;
    f32x4 c3;
    #pragma unroll
    for (int t = 0; t < 4; ++t) {
        int j = 4 * g + t;
        A3[t] = (f16)(b16 < 8 ? d1_w[j * 8 + b16] : 0.f);
        c3[t] = d1_b[min(j, 7)];
    }
    float ow[4];
    #pragma unroll
    for (int r = 0; r < 4; ++r)
        ow[r] = (g < 2) ? out_w[min(4 * g + r, 7)] : 0.f;
    const float ob = out_b[0];
    const f32x4 zero4 = {0.f, 0.f, 0.f, 0.f};

    // ---- pads: slot0 of each elem + 2 guard slots ----
    const uint4 PAD = make_uint4(0u, 0u, 0u, 0x3C000000u);
    if (lane < 32) *(uint4*)(xs + lane * EPW) = PAD;
    if (lane < 2)  *(uint4*)(xs + 32 * EPW + 4 * lane) = PAD;

    // ---- dummy 1.0 halves: 32 elems x 20 rows = 640 = 10 full rounds ----
    #pragma unroll
    for (int k = 0; k < 10; ++k) {
        int t = lane + 64 * k;
        int e2 = t / 20, rr = t - e2 * 20;
        *(f16*)((char*)xs + e2 * 336 + (rr + 1) * 16 + 14) = (f16)1.0f;
    }

    // ---- stage x: tid-linear float4 (each 64B line touched ONCE) ----
    {
        const float4* xsrc = (const float4*)(x + BE * 140);   // 1120 groups
        #pragma unroll
        for (int k = 0; k < 18; ++k) {
            int g4 = lane + 64 * k;
            if (g4 < 1120) {
                float4 v = xsrc[g4];
                int e = g4 / 35, j = g4 - e * 35;
                int p = 4 * j;                     // flat float idx 0..136
                int r = p / 7, c = p - 7 * r;
                char* eb = (char*)xs + e * 336;
                #pragma unroll
                for (int i = 0; i < 4; ++i) {      // (r, c+i), single wrap
                    int ci = c + i;
                    int wrap = (ci >= 7) ? 1 : 0;
                    int ri = r + wrap;
                    ci -= 7 * wrap;
                    float val = (i == 0) ? v.x : (i == 1) ? v.y
                              : (i == 2) ? v.z : v.w;
                    *(f16*)(eb + (ri + 1) * 16 + 2 * ci) = (f16)val;
                }
            }
        }
    }

    // ---- wave-local fence (single-wave block; rule #18) ----
    asm volatile("s_waitcnt lgkmcnt(0)" ::: "memory");
    __builtin_amdgcn_sched_barrier(0);

    // read bases; chain c elem = c*16 + b16; step l: +16B
    const uint* rb0 = xs + b16 * EPW + 4 * g;
    const uint* rb1 = rb0 + 16 * EPW;

    // ---- Phase A: conv + relu, both chains, full unroll ----
    f16x4 B2sA[LSEQ], B2sB[LSEQ];
    #pragma unroll
    for (int l = 0; l < LSEQ; ++l) {
        UB128 B1a, B1b;
        B1a.q = *(const uint4*)(rb0 + 4 * l);
        B1b.q = *(const uint4*)(rb1 + 4 * l);
        f32x4 a1a = __builtin_amdgcn_mfma_f32_16x16x32_f16(A1, B1a.v, zero4, 0, 0, 0);
        f32x4 a1b = __builtin_amdgcn_mfma_f32_16x16x32_f16(A1, B1b.v, zero4, 0, 0, 0);
        UB64 Ba, Bb;
        Ba.p[0] = __builtin_amdgcn_cvt_pkrtz(fmaxf(a1a[0], 0.f), fmaxf(a1a[1], 0.f));
        Ba.p[1] = __builtin_amdgcn_cvt_pkrtz(fmaxf(a1a[2], 0.f), fmaxf(a1a[3], 0.f));
        Bb.p[0] = __builtin_amdgcn_cvt_pkrtz(fmaxf(a1b[0], 0.f), fmaxf(a1b[1], 0.f));
        Bb.p[1] = __builtin_amdgcn_cvt_pkrtz(fmaxf(a1b[2], 0.f), fmaxf(a1b[3], 0.f));
        B2sA[l] = Ba.v;
        B2sB[l] = Bb.v;
    }

    // ---- Phase B: two independent serial recurrences, interleaved ----
    f16x4 H0 = {}, H1 = {};
    #pragma unroll
    for (int l = 0; l < LSEQ; ++l) {
        f32x4 a20 = __builtin_amdgcn_mfma_f32_16x16x16f16(A2, B2sA[l], rbp, 0, 0, 0);
        f32x4 a21 = __builtin_amdgcn_mfma_f32_16x16x16f16(A2, B2sB[l], rbp, 0, 0, 0);
        a20 = __builtin_amdgcn_mfma_f32_16x16x16f16(AU, H0, a20, 0, 0, 0);
        a21 = __builtin_amdgcn_mfma_f32_16x16x16f16(AU, H1, a21, 0, 0, 0);
        float t00 = __builtin_amdgcn_rcpf(1.f + __builtin_amdgcn_exp2f(a20[0]));
        float t01 = __builtin_amdgcn_rcpf(1.f + __builtin_amdgcn_exp2f(a20[1]));
        float t02 = __builtin_amdgcn_rcpf(1.f + __builtin_amdgcn_exp2f(a20[2]));
        float t03 = __builtin_amdgcn_rcpf(1.f + __builtin_amdgcn_exp2f(a20[3]));
        float t10 = __builtin_amdgcn_rcpf(1.f + __builtin_amdgcn_exp2f(a21[0]));
        float t11 = __builtin_amdgcn_rcpf(1.f + __builtin_amdgcn_exp2f(a21[1]));
        float t12 = __builtin_amdgcn_rcpf(1.f + __builtin_amdgcn_exp2f(a21[2]));
        float t13 = __builtin_amdgcn_rcpf(1.f + __builtin_amdgcn_exp2f(a21[3]));
        UB64 Hn0, Hn1;
        Hn0.p[0] = __builtin_amdgcn_cvt_pkrtz(fmaf(-2.f, t00, 1.f), fmaf(-2.f, t01, 1.f));
        Hn0.p[1] = __builtin_amdgcn_cvt_pkrtz(fmaf(-2.f, t02, 1.f), fmaf(-2.f, t03, 1.f));
        Hn1.p[0] = __builtin_amdgcn_cvt_pkrtz(fmaf(-2.f, t10, 1.f), fmaf(-2.f, t11, 1.f));
        Hn1.p[1] = __builtin_amdgcn_cvt_pkrtz(fmaf(-2.f, t12, 1.f), fmaf(-2.f, t13, 1.f));
        H0 = Hn0.v;
        H1 = Hn1.v;
    }

    // ---- head via MFMA ----
    f32x4 a30 = __builtin_amdgcn_mfma_f32_16x16x16f16(A3, H0, c3, 0, 0, 0);
    f32x4 a31 = __builtin_amdgcn_mfma_f32_16x16x16f16(A3, H1, c3, 0, 0, 0);
    float p0 = 0.f, p1 = 0.f;
    #pragma unroll
    for (int r = 0; r < 4; ++r) {
        p0 = fmaf(fmaxf(a30[r], 0.f), ow[r], p0);
        p1 = fmaf(fmaxf(a31[r], 0.f), ow[r], p1);
    }
    p0 += __shfl_xor(p0, 16); p0 += __shfl_xor(p0, 32);
    p1 += __shfl_xor(p1, 16); p1 += __shfl_xor(p1, 32);
    if (lane < 16) {
        out[BE + b16]      = p0 + ob;
        out[BE + 16 + b16] = p1 + ob;
    }
}

extern "C" void kernel_launch(void* const* d_in, const int* in_sizes, int n_in,
                              void* d_out, int out_size, void* d_ws, size_t ws_size,
                              hipStream_t stream) {
    const float* x      = (const float*)d_in[0];
    const float* conv_w = (const float*)d_in[1];
    const float* conv_b = (const float*)d_in[2];
    const float* rnn_w  = (const float*)d_in[3];
    const float* rnn_u  = (const float*)d_in[4];
    const float* rnn_b  = (const float*)d_in[5];
    const float* d1_w   = (const float*)d_in[6];
    const float* d1_b   = (const float*)d_in[7];
    const float* out_w  = (const float*)d_in[8];
    const float* out_b  = (const float*)d_in[9];
    float* out = (float*)d_out;

    const int B = out_size;                 // 262144
    const int grid = B / 32;                // 8192 single-wave blocks
    hybrid_fwd<<<grid, BLK, 0, stream>>>(x, conv_w, conv_b, rnn_w, rnn_u, rnn_b,
                                         d1_w, d1_b, out_w, out_b, out);
}

// Round 21
// 41.143 us; speedup vs baseline: 1.3446x; 1.3446x over previous
//
#include <hip/hip_runtime.h>

// SimpleHybridModel via MFMA, all-transposed chaining:
//  conv1d(k=3,SAME,relu) -> SimpleRNN(16,tanh) -> dense(8,relu) -> dense(1)
//
// R21 = R18 (39.7us best) with ROW-PER-LANE staging:
//  - R18's L1 wall: 35 float2 loads @280B lane stride = 2240 line-touches/
//    wave x 32 waves/CU ~= 30us of L1 service = the observed time. R20's fix
//    cut loads but paid 72 b16 scatter-writes (4.2M conflicts) -> net loss.
//  - R21: lane owns one 7-float row per round (640 rows = 10 rounds):
//    2 OVERLAPPING dwordx4 (floats 0-3, 3-6; 4B-aligned) -> 4 pkrtz ->
//    ONE aligned ds_write_b128 (R18's exact write pattern). Line-touches
//    560/wave (4x fewer), VMEM 20 instrs, writes unchanged.
//  - dummy-1.0 pass deleted: pkrtz(f6, 1.0) bakes it into every row write.
// Retained from R18: single-wave blocks (BLK=64, 32 elems, 2 chains/lane,
// 14 blocks/CU = 448 resident elems), no __syncthreads (lgkmcnt fence +
// sched_barrier, rule #18), 21-slot f16 element layout (slot0 pad
// (0..0,1.0h); slot l+g read as one aligned ds_read_b128; elem e row-20
// read = elem e+1's pad; k=31 conv-bias tap vs dummy-1.0 half; 2 guard
// slots), conv bias rides MFMA, 2*log2e folded into A2/AU/rnn_b, rcp+exp2
// tanh, packed cvts, head via MFMA.

#define BLK 64
#define LSEQ 20
#define EPW 84              // dwords per element: 21 slots * 4 (336 B)
#define LOG2E2 2.8853900817779268f

typedef _Float16 f16;
typedef __fp16   fp16x2 __attribute__((ext_vector_type(2)));
typedef _Float16 f16x4 __attribute__((ext_vector_type(4)));
typedef _Float16 f16x8 __attribute__((ext_vector_type(8)));
typedef float    f32x4 __attribute__((ext_vector_type(4)));

union UB128 { uint4 q; f16x8 v; };
union UB64  { f16x4 v; fp16x2 p[2]; };
union HU    { fp16x2 p; uint u; };

__global__ __launch_bounds__(BLK, 4) void hybrid_fwd(
    const float* __restrict__ x,
    const float* __restrict__ conv_w, const float* __restrict__ conv_b,
    const float* __restrict__ rnn_w,  const float* __restrict__ rnn_u,
    const float* __restrict__ rnn_b,
    const float* __restrict__ d1_w,   const float* __restrict__ d1_b,
    const float* __restrict__ out_w,  const float* __restrict__ out_b,
    float* __restrict__ out)
{
    __shared__ __align__(16) uint xs[32 * EPW + 8];   // 10784 B

    const int lane = threadIdx.x;                 // single wave
    const int b16  = lane & 15, g = lane >> 4;
    const long BE  = (long)blockIdx.x * 32;       // block's first elem

    // ---- weight fragments FIRST (VMEM latency overlaps staging below) ----
    f16x8 A1;
    #pragma unroll
    for (int t = 0; t < 8; ++t) {
        float wv = conv_w[min(g * 7 + t, 20) * 16 + b16];
        float sel = (g < 3 && t < 7) ? wv
                  : ((g == 3 && t == 7) ? conv_b[b16] : 0.f);
        A1[t] = (f16)sel;
    }
    f16x4 A2, AU;
    f32x4 rbp;
    #pragma unroll
    for (int t = 0; t < 4; ++t) {
        A2[t]  = (f16)(LOG2E2 * rnn_w[(4 * g + t) * 16 + b16]);
        AU[t]  = (f16)(LOG2E2 * rnn_u[(4 * g + t) * 16 + b16]);
        rbp[t] = LOG2E2 * rnn_b[4 * g + t];
    }
    f16x4 A3;
    f32x4 c3;
    #pragma unroll
    for (int t = 0; t < 4; ++t) {
        int j = 4 * g + t;
        A3[t] = (f16)(b16 < 8 ? d1_w[j * 8 + b16] : 0.f);
        c3[t] = d1_b[min(j, 7)];
    }
    float ow[4];
    #pragma unroll
    for (int r = 0; r < 4; ++r)
        ow[r] = (g < 2) ? out_w[min(4 * g + r, 7)] : 0.f;
    const float ob = out_b[0];
    const f32x4 zero4 = {0.f, 0.f, 0.f, 0.f};

    // ---- pads: slot0 of each elem + 2 guard slots ----
    const uint4 PAD = make_uint4(0u, 0u, 0u, 0x3C000000u);
    if (lane < 32) *(uint4*)(xs + lane * EPW) = PAD;
    if (lane < 2)  *(uint4*)(xs + 32 * EPW + 4 * lane) = PAD;

    // ---- stage x: ROW-PER-LANE. flat-row = lane + 64k (640 rows, 10 rds) --
    // 2 overlapping dwordx4 per row (floats 0-3, 3-6) -> 4 pkrtz ->
    // one aligned ds_write_b128 to slot r+1 (dummy 1.0 rides pkrtz).
    {
        const float* xg = x + BE * 140;
        #pragma unroll
        for (int k = 0; k < 10; ++k) {
            int rowflat = lane + 64 * k;
            int e = rowflat / 20;                 // compiler: magic-mul
            int r = rowflat - e * 20;
            const float* rp = xg + e * 140 + r * 7;
            float4 v0 = *(const float4*)(rp);     // floats 0..3
            float4 v1 = *(const float4*)(rp + 3); // floats 3..6 (4B-aligned)
            HU h0, h1, h2, h3;
            h0.p = __builtin_amdgcn_cvt_pkrtz(v0.x, v0.y);
            h1.p = __builtin_amdgcn_cvt_pkrtz(v0.z, v0.w);
            h2.p = __builtin_amdgcn_cvt_pkrtz(v1.y, v1.z);
            h3.p = __builtin_amdgcn_cvt_pkrtz(v1.w, 1.0f);   // dummy 1.0
            uint4 val; val.x = h0.u; val.y = h1.u; val.z = h2.u; val.w = h3.u;
            *(uint4*)(xs + e * EPW + 4 * (r + 1)) = val;     // 16B aligned
        }
    }

    // ---- wave-local fence (single-wave block; rule #18) ----
    asm volatile("s_waitcnt lgkmcnt(0)" ::: "memory");
    __builtin_amdgcn_sched_barrier(0);

    // read bases; chain c elem = c*16 + b16; step l: +16B
    const uint* rb0 = xs + b16 * EPW + 4 * g;
    const uint* rb1 = rb0 + 16 * EPW;

    // ---- Phase A: conv + relu, both chains, full unroll ----
    f16x4 B2sA[LSEQ], B2sB[LSEQ];
    #pragma unroll
    for (int l = 0; l < LSEQ; ++l) {
        UB128 B1a, B1b;
        B1a.q = *(const uint4*)(rb0 + 4 * l);
        B1b.q = *(const uint4*)(rb1 + 4 * l);
        f32x4 a1a = __builtin_amdgcn_mfma_f32_16x16x32_f16(A1, B1a.v, zero4, 0, 0, 0);
        f32x4 a1b = __builtin_amdgcn_mfma_f32_16x16x32_f16(A1, B1b.v, zero4, 0, 0, 0);
        UB64 Ba, Bb;
        Ba.p[0] = __builtin_amdgcn_cvt_pkrtz(fmaxf(a1a[0], 0.f), fmaxf(a1a[1], 0.f));
        Ba.p[1] = __builtin_amdgcn_cvt_pkrtz(fmaxf(a1a[2], 0.f), fmaxf(a1a[3], 0.f));
        Bb.p[0] = __builtin_amdgcn_cvt_pkrtz(fmaxf(a1b[0], 0.f), fmaxf(a1b[1], 0.f));
        Bb.p[1] = __builtin_amdgcn_cvt_pkrtz(fmaxf(a1b[2], 0.f), fmaxf(a1b[3], 0.f));
        B2sA[l] = Ba.v;
        B2sB[l] = Bb.v;
    }

    // ---- Phase B: two independent serial recurrences, interleaved ----
    f16x4 H0 = {}, H1 = {};
    #pragma unroll
    for (int l = 0; l < LSEQ; ++l) {
        f32x4 a20 = __builtin_amdgcn_mfma_f32_16x16x16f16(A2, B2sA[l], rbp, 0, 0, 0);
        f32x4 a21 = __builtin_amdgcn_mfma_f32_16x16x16f16(A2, B2sB[l], rbp, 0, 0, 0);
        a20 = __builtin_amdgcn_mfma_f32_16x16x16f16(AU, H0, a20, 0, 0, 0);
        a21 = __builtin_amdgcn_mfma_f32_16x16x16f16(AU, H1, a21, 0, 0, 0);
        float t00 = __builtin_amdgcn_rcpf(1.f + __builtin_amdgcn_exp2f(a20[0]));
        float t01 = __builtin_amdgcn_rcpf(1.f + __builtin_amdgcn_exp2f(a20[1]));
        float t02 = __builtin_amdgcn_rcpf(1.f + __builtin_amdgcn_exp2f(a20[2]));
        float t03 = __builtin_amdgcn_rcpf(1.f + __builtin_amdgcn_exp2f(a20[3]));
        float t10 = __builtin_amdgcn_rcpf(1.f + __builtin_amdgcn_exp2f(a21[0]));
        float t11 = __builtin_amdgcn_rcpf(1.f + __builtin_amdgcn_exp2f(a21[1]));
        float t12 = __builtin_amdgcn_rcpf(1.f + __builtin_amdgcn_exp2f(a21[2]));
        float t13 = __builtin_amdgcn_rcpf(1.f + __builtin_amdgcn_exp2f(a21[3]));
        UB64 Hn0, Hn1;
        Hn0.p[0] = __builtin_amdgcn_cvt_pkrtz(fmaf(-2.f, t00, 1.f), fmaf(-2.f, t01, 1.f));
        Hn0.p[1] = __builtin_amdgcn_cvt_pkrtz(fmaf(-2.f, t02, 1.f), fmaf(-2.f, t03, 1.f));
        Hn1.p[0] = __builtin_amdgcn_cvt_pkrtz(fmaf(-2.f, t10, 1.f), fmaf(-2.f, t11, 1.f));
        Hn1.p[1] = __builtin_amdgcn_cvt_pkrtz(fmaf(-2.f, t12, 1.f), fmaf(-2.f, t13, 1.f));
        H0 = Hn0.v;
        H1 = Hn1.v;
    }

    // ---- head via MFMA ----
    f32x4 a30 = __builtin_amdgcn_mfma_f32_16x16x16f16(A3, H0, c3, 0, 0, 0);
    f32x4 a31 = __builtin_amdgcn_mfma_f32_16x16x16f16(A3, H1, c3, 0, 0, 0);
    float p0 = 0.f, p1 = 0.f;
    #pragma unroll
    for (int r = 0; r < 4; ++r) {
        p0 = fmaf(fmaxf(a30[r], 0.f), ow[r], p0);
        p1 = fmaf(fmaxf(a31[r], 0.f), ow[r], p1);
    }
    p0 += __shfl_xor(p0, 16); p0 += __shfl_xor(p0, 32);
    p1 += __shfl_xor(p1, 16); p1 += __shfl_xor(p1, 32);
    if (lane < 16) {
        out[BE + b16]      = p0 + ob;
        out[BE + 16 + b16] = p1 + ob;
    }
}

extern "C" void kernel_launch(void* const* d_in, const int* in_sizes, int n_in,
                              void* d_out, int out_size, void* d_ws, size_t ws_size,
                              hipStream_t stream) {
    const float* x      = (const float*)d_in[0];
    const float* conv_w = (const float*)d_in[1];
    const float* conv_b = (const float*)d_in[2];
    const float* rnn_w  = (const float*)d_in[3];
    const float* rnn_u  = (const float*)d_in[4];
    const float* rnn_b  = (const float*)d_in[5];
    const float* d1_w   = (const float*)d_in[6];
    const float* d1_b   = (const float*)d_in[7];
    const float* out_w  = (const float*)d_in[8];
    const float* out_b  = (const float*)d_in[9];
    float* out = (float*)d_out;

    const int B = out_size;                 // 262144
    const int grid = B / 32;                // 8192 single-wave blocks
    hybrid_fwd<<<grid, BLK, 0, stream>>>(x, conv_w, conv_b, rnn_w, rnn_u, rnn_b,
                                         d1_w, d1_b, out_w, out_b, out);
}

// Round 22
// 39.145 us; speedup vs baseline: 1.4133x; 1.0510x over previous
//
#include <hip/hip_runtime.h>

// SimpleHybridModel via MFMA, all-transposed chaining:
//  conv1d(k=3,SAME,relu) -> SimpleRNN(16,tanh) -> dense(8,relu) -> dense(1)
//
// R22 = R18 with PAD-FREE 20-slot layout -> 16 blocks/CU (hardware cap).
//  - Validated model: throughput ~ resident elems/CU (R18 +17% res -> +10%;
//    R16 -43% res -> -36%). LDS granule is 512B: R18's 10784B rounds to
//    11264 -> 14 blocks. New layout: 20 slots x 16B = 320B/elem, 32 elems =
//    10240B EXACTLY -> 16 blocks/CU = 512 resident elems (+14%).
//  - SAME-padding moved from data into the A-operand: A1_0 (g=0 taps zeroed)
//    at l=0, A1_19 (g=2 taps zeroed) at l=19. Boundary reads hit neighbor
//    elements' real rows (finite garbage) and are annihilated by zero A.
//  - g=3 (bias) lanes read slot l of their own element: every row carries
//    dummy 1.0 at half 7, so 1.0*conv_b rides the MFMA at every step.
//  - Two OOB edges (elem0 l=0 g=0; elem31 l=19 g=2) use cndmask-redirected
//    in-bounds addresses (content irrelevant: those lanes' A is zero).
// Retained from R18: single-wave blocks, 2 chains/lane, phase-split full
// unroll, float2 staging (2 lanes/elem), lgkmcnt fence + sched_barrier
// (rule #18), conv bias rides MFMA, 2*log2e folded into A2/AU/rnn_b,
// rcp+exp2 tanh, packed cvts, head via MFMA.

#define BLK 64
#define LSEQ 20
#define EPW 80              // dwords per element: 20 slots * 4 (320 B)
#define LOG2E2 2.8853900817779268f

typedef _Float16 f16;
typedef __fp16   fp16x2 __attribute__((ext_vector_type(2)));
typedef _Float16 f16x4 __attribute__((ext_vector_type(4)));
typedef _Float16 f16x8 __attribute__((ext_vector_type(8)));
typedef float    f32x4 __attribute__((ext_vector_type(4)));

union UB128 { uint4 q; f16x8 v; };
union UB64  { f16x4 v; fp16x2 p[2]; };
union HU    { fp16x2 p; uint u; };

__global__ __launch_bounds__(BLK, 4) void hybrid_fwd(
    const float* __restrict__ x,
    const float* __restrict__ conv_w, const float* __restrict__ conv_b,
    const float* __restrict__ rnn_w,  const float* __restrict__ rnn_u,
    const float* __restrict__ rnn_b,
    const float* __restrict__ d1_w,   const float* __restrict__ d1_b,
    const float* __restrict__ out_w,  const float* __restrict__ out_b,
    float* __restrict__ out)
{
    __shared__ __align__(16) uint xs[32 * EPW];   // 10240 B EXACT (16/CU)

    const int lane = threadIdx.x;                 // single wave
    const int b16  = lane & 15, g = lane >> 4;
    const long BE  = (long)blockIdx.x * 32;       // block's first elem

    // ---- weight fragments FIRST (VMEM latency overlaps staging below) ----
    f16x8 A1;
    #pragma unroll
    for (int t = 0; t < 8; ++t) {
        float wv = conv_w[min(g * 7 + t, 20) * 16 + b16];
        float sel = (g < 3 && t < 7) ? wv
                  : ((g == 3 && t == 7) ? conv_b[b16] : 0.f);
        A1[t] = (f16)sel;
    }
    const f16x8 A1z = {};
    const f16x8 A1_0  = (g == 0) ? A1z : A1;   // l=0:  row -1 contribution = 0
    const f16x8 A1_19 = (g == 2) ? A1z : A1;   // l=19: row 20 contribution = 0
    f16x4 A2, AU;
    f32x4 rbp;
    #pragma unroll
    for (int t = 0; t < 4; ++t) {
        A2[t]  = (f16)(LOG2E2 * rnn_w[(4 * g + t) * 16 + b16]);
        AU[t]  = (f16)(LOG2E2 * rnn_u[(4 * g + t) * 16 + b16]);
        rbp[t] = LOG2E2 * rnn_b[4 * g + t];
    }
    f16x4 A3;
    f32x4 c3;
    #pragma unroll
    for (int t = 0; t < 4; ++t) {
        int j = 4 * g + t;
        A3[t] = (f16)(b16 < 8 ? d1_w[j * 8 + b16] : 0.f);
        c3[t] = d1_b[min(j, 7)];
    }
    float ow[4];
    #pragma unroll
    for (int r = 0; r < 4; ++r)
        ow[r] = (g < 2) ? out_w[min(4 * g + r, 7)] : 0.f;
    const float ob = out_b[0];
    const f32x4 zero4 = {0.f, 0.f, 0.f, 0.f};

    // ---- stage x: 2 lanes/elem (R18 pattern), rows -> slot r (no pad) ----
    {
        const int e = lane & 31;                  // staged elem
        const int h = lane >> 5;                  // half: rows 10h..10h+9
        const float2* sp = (const float2*)(x + (BE + e) * 140 + h * 70);
        float2 f2[35];
        #pragma unroll
        for (int i = 0; i < 35; ++i) f2[i] = sp[i];
        const float* f = (const float*)f2;        // static-indexed
        uint* eb = xs + e * EPW;
        #pragma unroll
        for (int i = 0; i < 10; ++i) {            // row r = 10h+i -> slot r
            HU h0, h1, h2, h3;
            h0.p = __builtin_amdgcn_cvt_pkrtz(f[7 * i + 0], f[7 * i + 1]);
            h1.p = __builtin_amdgcn_cvt_pkrtz(f[7 * i + 2], f[7 * i + 3]);
            h2.p = __builtin_amdgcn_cvt_pkrtz(f[7 * i + 4], f[7 * i + 5]);
            h3.p = __builtin_amdgcn_cvt_pkrtz(f[7 * i + 6], 1.0f);   // dummy
            uint4 val; val.x = h0.u; val.y = h1.u; val.z = h2.u; val.w = h3.u;
            *(uint4*)(eb + 4 * (10 * h + i)) = val;   // 16B aligned
        }
    }

    // ---- wave-local fence (single-wave block; rule #18) ----
    asm volatile("s_waitcnt lgkmcnt(0)" ::: "memory");
    __builtin_amdgcn_sched_barrier(0);

    // ---- read pointers: tap g reads slot l-1+g (g<=2); g=3 reads slot l ----
    const int d = (g == 3) ? 0 : (g - 1);         // slot delta vs l
    const uint* p0 = xs + b16 * EPW + 4 * d;             // chain A (elem b16)
    const uint* p1 = xs + (16 + b16) * EPW + 4 * d;      // chain B (elem 16+b16)
    // OOB edge redirects (content annihilated by A1_0 / A1_19):
    const uint* q0a  = (b16 == 0  && g == 0) ? xs : p0;                  // l=0, chain A
    const uint* q19b = (b16 == 15 && g == 2) ? (xs + 31 * EPW) : (p1 + 76); // l=19, chain B

    // ---- Phase A: conv + relu, both chains, full unroll ----
    f16x4 B2sA[LSEQ], B2sB[LSEQ];
    #pragma unroll
    for (int l = 0; l < LSEQ; ++l) {
        const f16x8 Al = (l == 0) ? A1_0 : (l == LSEQ - 1) ? A1_19 : A1;
        const uint* aA = (l == 0) ? q0a : (p0 + 4 * l);
        const uint* aB = (l == LSEQ - 1) ? q19b : (p1 + 4 * l);
        UB128 B1a, B1b;
        B1a.q = *(const uint4*)aA;
        B1b.q = *(const uint4*)aB;
        f32x4 a1a = __builtin_amdgcn_mfma_f32_16x16x32_f16(Al, B1a.v, zero4, 0, 0, 0);
        f32x4 a1b = __builtin_amdgcn_mfma_f32_16x16x32_f16(Al, B1b.v, zero4, 0, 0, 0);
        UB64 Ba, Bb;
        Ba.p[0] = __builtin_amdgcn_cvt_pkrtz(fmaxf(a1a[0], 0.f), fmaxf(a1a[1], 0.f));
        Ba.p[1] = __builtin_amdgcn_cvt_pkrtz(fmaxf(a1a[2], 0.f), fmaxf(a1a[3], 0.f));
        Bb.p[0] = __builtin_amdgcn_cvt_pkrtz(fmaxf(a1b[0], 0.f), fmaxf(a1b[1], 0.f));
        Bb.p[1] = __builtin_amdgcn_cvt_pkrtz(fmaxf(a1b[2], 0.f), fmaxf(a1b[3], 0.f));
        B2sA[l] = Ba.v;
        B2sB[l] = Bb.v;
    }

    // ---- Phase B: two independent serial recurrences, interleaved ----
    f16x4 H0 = {}, H1 = {};
    #pragma unroll
    for (int l = 0; l < LSEQ; ++l) {
        f32x4 a20 = __builtin_amdgcn_mfma_f32_16x16x16f16(A2, B2sA[l], rbp, 0, 0, 0);
        f32x4 a21 = __builtin_amdgcn_mfma_f32_16x16x16f16(A2, B2sB[l], rbp, 0, 0, 0);
        a20 = __builtin_amdgcn_mfma_f32_16x16x16f16(AU, H0, a20, 0, 0, 0);
        a21 = __builtin_amdgcn_mfma_f32_16x16x16f16(AU, H1, a21, 0, 0, 0);
        float t00 = __builtin_amdgcn_rcpf(1.f + __builtin_amdgcn_exp2f(a20[0]));
        float t01 = __builtin_amdgcn_rcpf(1.f + __builtin_amdgcn_exp2f(a20[1]));
        float t02 = __builtin_amdgcn_rcpf(1.f + __builtin_amdgcn_exp2f(a20[2]));
        float t03 = __builtin_amdgcn_rcpf(1.f + __builtin_amdgcn_exp2f(a20[3]));
        float t10 = __builtin_amdgcn_rcpf(1.f + __builtin_amdgcn_exp2f(a21[0]));
        float t11 = __builtin_amdgcn_rcpf(1.f + __builtin_amdgcn_exp2f(a21[1]));
        float t12 = __builtin_amdgcn_rcpf(1.f + __builtin_amdgcn_exp2f(a21[2]));
        float t13 = __builtin_amdgcn_rcpf(1.f + __builtin_amdgcn_exp2f(a21[3]));
        UB64 Hn0, Hn1;
        Hn0.p[0] = __builtin_amdgcn_cvt_pkrtz(fmaf(-2.f, t00, 1.f), fmaf(-2.f, t01, 1.f));
        Hn0.p[1] = __builtin_amdgcn_cvt_pkrtz(fmaf(-2.f, t02, 1.f), fmaf(-2.f, t03, 1.f));
        Hn1.p[0] = __builtin_amdgcn_cvt_pkrtz(fmaf(-2.f, t10, 1.f), fmaf(-2.f, t11, 1.f));
        Hn1.p[1] = __builtin_amdgcn_cvt_pkrtz(fmaf(-2.f, t12, 1.f), fmaf(-2.f, t13, 1.f));
        H0 = Hn0.v;
        H1 = Hn1.v;
    }

    // ---- head via MFMA ----
    f32x4 a30 = __builtin_amdgcn_mfma_f32_16x16x16f16(A3, H0, c3, 0, 0, 0);
    f32x4 a31 = __builtin_amdgcn_mfma_f32_16x16x16f16(A3, H1, c3, 0, 0, 0);
    float p0h = 0.f, p1h = 0.f;
    #pragma unroll
    for (int r = 0; r < 4; ++r) {
        p0h = fmaf(fmaxf(a30[r], 0.f), ow[r], p0h);
        p1h = fmaf(fmaxf(a31[r], 0.f), ow[r], p1h);
    }
    p0h += __shfl_xor(p0h, 16); p0h += __shfl_xor(p0h, 32);
    p1h += __shfl_xor(p1h, 16); p1h += __shfl_xor(p1h, 32);
    if (lane < 16) {
        out[BE + b16]      = p0h + ob;
        out[BE + 16 + b16] = p1h + ob;
    }
}

extern "C" void kernel_launch(void* const* d_in, const int* in_sizes, int n_in,
                              void* d_out, int out_size, void* d_ws, size_t ws_size,
                              hipStream_t stream) {
    const float* x      = (const float*)d_in[0];
    const float* conv_w = (const float*)d_in[1];
    const float* conv_b = (const float*)d_in[2];
    const float* rnn_w  = (const float*)d_in[3];
    const float* rnn_u  = (const float*)d_in[4];
    const float* rnn_b  = (const float*)d_in[5];
    const float* d1_w   = (const float*)d_in[6];
    const float* d1_b   = (const float*)d_in[7];
    const float* out_w  = (const float*)d_in[8];
    const float* out_b  = (const float*)d_in[9];
    float* out = (float*)d_out;

    const int B = out_size;                 // 262144
    const int grid = B / 32;                // 8192 single-wave blocks
    hybrid_fwd<<<grid, BLK, 0, stream>>>(x, conv_w, conv_b, rnn_w, rnn_u, rnn_b,
                                         d1_w, d1_b, out_w, out_b, out);
}